// Round 2
// baseline (135553.308 us; speedup 1.0000x reference)
//
#include <hip/hip_runtime.h>
#include <hip/hip_cooperative_groups.h>
#include <cstdint>
#include <cstddef>

namespace cg = cooperative_groups;

// ---------------------------------------------------------------------------
// Seq2SeqNet: bidir GRU encoder (1024 steps) + attention GRU greedy decoder
// (256 steps). ALL math fp32, phase bodies bit-identical to the verified
// multi-launch kernel (greedy argmax feedback: ANY reassociation can flip a
// token). This revision wraps the per-step kernels in persistent cooperative
// kernels (grid.sync between phases) to kill launch overhead, with runtime
// fallback to the proven per-step launch sequence if cooperative launch is
// rejected. Encoder Whh weights are cached in LDS across all 1024 steps.
// ---------------------------------------------------------------------------

constexpr int kH = 512, kH2 = 256, kVC = 2000, kB = 64, kLIN = 1024, kT = 256;
constexpr int kSTART = 1;

// -------------------------------------------------------------------- zero
__global__ __launch_bounds__(256) void k_zero(float* p, int n) {
  int i = blockIdx.x * 256 + threadIdx.x;
  if (i < n) p[i] = 0.f;
}

// ------------------------------------------- encoder input-gate token table
__global__ __launch_bounds__(256)
void k_gi_table(const float* emb_jamo, const float* Wf, const float* Wb,
                const float* bihf, const float* bihb, float* gi) {
  int v = blockIdx.x >> 1, d = blockIdx.x & 1;
  const float* W = d ? Wb : Wf;
  const float* bih = d ? bihb : bihf;
  __shared__ float x[kH];
  for (int k = threadIdx.x; k < kH; k += 256) x[k] = emb_jamo[v * kH + k];
  __syncthreads();
  for (int j = threadIdx.x; j < 3 * kH2; j += 256) {
    float acc = bih[j];
    const float* row = W + (size_t)j * kH;
    for (int k = 0; k < kH; k += 4) {
      float4 f = *(const float4*)(row + k);
      acc += x[k] * f.x + x[k + 1] * f.y + x[k + 2] * f.z + x[k + 3] * f.w;
    }
    gi[(size_t)(v * 2 + d) * 768 + j] = acc;
  }
}

// ------------------ decoder embedding tables (bias folded)
__global__ __launch_bounds__(256)
void k_ac_emb(const float* emb_char, const float* attn_W, const float* attn_b,
              const float* comb_W, const float* comb_b, float* A, float* C) {
  int v = blockIdx.x;
  __shared__ float x[kH];
  for (int k = threadIdx.x; k < kH; k += 256) x[k] = emb_char[v * kH + k];
  __syncthreads();
  for (int j = threadIdx.x; j < kH; j += 256) {
    float a = attn_b[j], c = comb_b[j];
    const float* ra = attn_W + (size_t)j * 1024;
    const float* rc = comb_W + (size_t)j * 1024;
    for (int k = 0; k < kH; k += 4) {
      float4 fa = *(const float4*)(ra + k), fc = *(const float4*)(rc + k);
      a += x[k] * fa.x + x[k + 1] * fa.y + x[k + 2] * fa.z + x[k + 3] * fa.w;
      c += x[k] * fc.x + x[k + 1] * fc.y + x[k + 2] * fc.z + x[k + 3] * fc.w;
    }
    A[(size_t)v * kH + j] = a;
    C[(size_t)v * kH + j] = c;
  }
}

// ======================= decoder phase bodies (verbatim ports) =============

// Phase A: scores + per-tile softmax partials + per-tile ctx partials.
// Bit-identical to original k_scores: two passes over the enc tile.
__device__ void phaseA(int b, int lt, int tid, const float* encAll,
                       const float* keyAll, float* sc, float* pm, float* pd,
                       float* pctx) {
  int lane = tid & 63, w = tid >> 6, hl = lane & 31, half = lane >> 5;
  __shared__ float s_tile[128], e_tile[128], red[128];
  const float* enc = encAll + (size_t)b * kLIN * kH;
  float kreg[16];
  const float* key = keyAll + (size_t)b * kH + hl * 16;
#pragma unroll
  for (int m = 0; m < 16; m += 4) *(float4*)(kreg + m) = *(const float4*)(key + m);
  for (int i = 0; i < 16; i++) {
    int ll = w * 32 + i * 2 + half;
    int l = lt * 128 + ll;
    const float* row = enc + (size_t)l * kH + hl * 16;
    float acc = 0.f;
#pragma unroll
    for (int m = 0; m < 16; m += 4) {
      float4 v = *(const float4*)(row + m);
      acc += v.x * kreg[m] + v.y * kreg[m + 1] + v.z * kreg[m + 2] + v.w * kreg[m + 3];
    }
#pragma unroll
    for (int m2 = 16; m2 > 0; m2 >>= 1) acc += __shfl_xor(acc, m2, 32);
    if (hl == 0) { s_tile[ll] = acc; sc[(size_t)b * kLIN + l] = acc; }
  }
  __syncthreads();
  if (tid < 128) red[tid] = s_tile[tid];
  __syncthreads();
  for (int s = 64; s > 0; s >>= 1) {
    if (tid < s) red[tid] = fmaxf(red[tid], red[tid + s]);
    __syncthreads();
  }
  float mt = red[0];
  __syncthreads();
  if (tid < 128) { e_tile[tid] = expf(s_tile[tid] - mt); red[tid] = e_tile[tid]; }
  __syncthreads();
  for (int s = 64; s > 0; s >>= 1) {
    if (tid < s) red[tid] += red[tid + s];
    __syncthreads();
  }
  float dt = red[0];
  int h0i = tid * 2;
  float cx = 0.f, cy = 0.f;
  const float* base = enc + (size_t)(lt * 128) * kH + h0i;
  for (int l = 0; l < 128; l++) {
    float e = e_tile[l];
    float2 v = *(const float2*)(base + (size_t)l * kH);
    cx += e * v.x; cy += e * v.y;
  }
  float* pc = pctx + ((size_t)b * 8 + lt) * kH;
  pc[h0i] = cx; pc[h0i + 1] = cy;
  if (tid == 0) { pm[b * 8 + lt] = mt; pd[b * 8 + lt] = dt; }
  __syncthreads();   // shared reuse guard (no numeric effect)
}

// Phase B: combine tile partials -> ctx, attention weights, g = relu(...)
__device__ void phaseB(int b, int tid, const float* cW, const float* Ctab,
                       const float* sc, const float* pm, const float* pd,
                       const float* pctx, const int* tok, float* out1,
                       float* gt, int BC, int b0, int t) {
  __shared__ float f8[8], MD[2], ctxl[kH];
  __shared__ int tokl;
  if (tid == 0) {
    float M = -1e30f;
    for (int i = 0; i < 8; i++) M = fmaxf(M, pm[b * 8 + i]);
    float D = 0.f;
    for (int i = 0; i < 8; i++) {
      float f = expf(pm[b * 8 + i] - M);
      f8[i] = f; D += f * pd[b * 8 + i];
    }
    MD[0] = M; MD[1] = 1.f / D;
    tokl = tok[b];
  }
  __syncthreads();
  float M = MD[0], invD = MD[1];
  int h0i = tid * 2;
  float cx = 0.f, cy = 0.f;
  for (int i = 0; i < 8; i++) {
    const float* pc = pctx + ((size_t)b * 8 + i) * kH + h0i;
    cx += f8[i] * pc[0]; cy += f8[i] * pc[1];
  }
  ctxl[h0i] = cx * invD; ctxl[h0i + 1] = cy * invD;
  int gb = b0 + b;
  for (int l = tid; l < kLIN; l += 256)
    out1[((size_t)gb * kLIN + l) * kT + t] = expf(sc[(size_t)b * kLIN + l] - M) * invD;
  __syncthreads();
  int tk = tokl;
  for (int j = tid; j < kH; j += 256) {
    const float* row = cW + (size_t)j * 1024 + 512;
    float acc = Ctab[(size_t)tk * kH + j];
    for (int k = 0; k < kH; k += 4) {
      float4 f = *(const float4*)(row + k);
      acc += ctxl[k] * f.x + ctxl[k + 1] * f.y + ctxl[k + 2] * f.z + ctxl[k + 3] * f.w;
    }
    gt[(size_t)j * BC + b] = fmaxf(acc, 0.f);
  }
  __syncthreads();   // shared reuse guard
}

// Phase C: decoder GRU, thread per (u, b)
__device__ void phaseC(int blk, int tid, const float* Wih, const float* Whh,
                       const float* bih, const float* bhh, const float* gt,
                       float* ht, float* hr, int BC, int lbc, int pp) {
  int b = tid & (BC - 1), q = tid >> lbc;
  int u = blk * (256 >> lbc) + q;
  const float* htp = ht + (size_t)pp * kH * BC;
  float air = bih[u], aiz = bih[kH + u], ain = bih[2 * kH + u];
  float ahr = bhh[u], ahz = bhh[kH + u], ahn = bhh[2 * kH + u];
  const float* wir = Wih + (size_t)(0 * kH + u) * kH;
  const float* wiz = Wih + (size_t)(1 * kH + u) * kH;
  const float* win = Wih + (size_t)(2 * kH + u) * kH;
  const float* whr = Whh + (size_t)(0 * kH + u) * kH;
  const float* whz = Whh + (size_t)(1 * kH + u) * kH;
  const float* whn = Whh + (size_t)(2 * kH + u) * kH;
  for (int k = 0; k < kH; k += 4) {
    float4 fir = *(const float4*)(wir + k), fiz = *(const float4*)(wiz + k), fin = *(const float4*)(win + k);
    float4 fhr = *(const float4*)(whr + k), fhz = *(const float4*)(whz + k), fhn = *(const float4*)(whn + k);
    float g0 = gt[(k + 0) * BC + b], g1 = gt[(k + 1) * BC + b];
    float g2 = gt[(k + 2) * BC + b], g3 = gt[(k + 3) * BC + b];
    float h0v = htp[(k + 0) * BC + b], h1v = htp[(k + 1) * BC + b];
    float h2v = htp[(k + 2) * BC + b], h3v = htp[(k + 3) * BC + b];
    air += g0 * fir.x + g1 * fir.y + g2 * fir.z + g3 * fir.w;
    aiz += g0 * fiz.x + g1 * fiz.y + g2 * fiz.z + g3 * fiz.w;
    ain += g0 * fin.x + g1 * fin.y + g2 * fin.z + g3 * fin.w;
    ahr += h0v * fhr.x + h1v * fhr.y + h2v * fhr.z + h3v * fhr.w;
    ahz += h0v * fhz.x + h1v * fhz.y + h2v * fhz.z + h3v * fhz.w;
    ahn += h0v * fhn.x + h1v * fhn.y + h2v * fhn.z + h3v * fhn.w;
  }
  float r = 1.f / (1.f + expf(-(air + ahr)));
  float z = 1.f / (1.f + expf(-(aiz + ahz)));
  float n = tanhf(ain + r * ahn);
  float hp = htp[(size_t)u * BC + b];
  float hnew = (1.f - z) * n + z * hp;
  ht[(size_t)(1 - pp) * kH * BC + (size_t)u * BC + b] = hnew;
  hr[(size_t)(1 - pp) * BC * kH + (size_t)b * kH + u] = hnew;
}

// Phase D: logits for one (b, c-tile of 250)
__device__ void phaseD(int b, int ct, int tid, const float* oW, const float* ob,
                       const float* hr, float* lg, int BC, int np) {
  int lane = tid & 63, w = tid >> 6, hl = lane & 31, half = lane >> 5;
  const float* hrow = hr + (size_t)np * BC * kH + (size_t)b * kH + hl * 16;
  float hreg[16];
#pragma unroll
  for (int m = 0; m < 16; m += 4) *(float4*)(hreg + m) = *(const float4*)(hrow + m);
  int c0 = ct * 250;
  for (int i = 0; i < 32; i++) {
    int c = c0 + i * 8 + w * 2 + half;
    if (c < c0 + 250) {
      const float* row = oW + (size_t)c * kH + hl * 16;
      float acc = 0.f;
#pragma unroll
      for (int m = 0; m < 16; m += 4) {
        float4 v = *(const float4*)(row + m);
        acc += v.x * hreg[m] + v.y * hreg[m + 1] + v.z * hreg[m + 2] + v.w * hreg[m + 3];
      }
#pragma unroll
      for (int m2 = 16; m2 > 0; m2 >>= 1) acc += __shfl_xor(acc, m2, 32);
      if (hl == 0) lg[(size_t)b * kVC + c] = acc + ob[c];
    }
  }
}

// Phase E: log_softmax + out0 + argmax + loss + next-step key
__device__ void phaseE(int b, int tid, const float* aW, const int* targets,
                       const float* mask, const float* Atab, const float* hr,
                       const float* lg, float* key, int* tok, float* loss,
                       float* out0, int BC, int b0, int t, int np) {
  int gb = b0 + b;
  __shared__ float rv[256]; __shared__ int ri[256]; __shared__ float rs[256];
  __shared__ float hsh[kH];
  const float* lrow = lg + (size_t)b * kVC;
  float xv[8];
  float bv = -3.4e38f; int bi = kVC;
#pragma unroll
  for (int i = 0; i < 8; i++) {
    int c = tid + i * 256;
    float x = (c < kVC) ? lrow[c] : -3.4e38f;
    xv[i] = x;
    if (x > bv) { bv = x; bi = c; }
  }
  rv[tid] = bv; ri[tid] = bi;
  __syncthreads();
  for (int s = 128; s > 0; s >>= 1) {
    if (tid < s) {
      float v2 = rv[tid + s]; int i2 = ri[tid + s];
      if (v2 > rv[tid] || (v2 == rv[tid] && i2 < ri[tid])) { rv[tid] = v2; ri[tid] = i2; }
    }
    __syncthreads();
  }
  float M = rv[0]; int nt = ri[0];
  float se = 0.f;
#pragma unroll
  for (int i = 0; i < 8; i++) { int c = tid + i * 256; if (c < kVC) se += expf(xv[i] - M); }
  rs[tid] = se;
  __syncthreads();
  for (int s = 128; s > 0; s >>= 1) {
    if (tid < s) rs[tid] += rs[tid + s];
    __syncthreads();
  }
  float lse = M + logf(rs[0]);
  float* orow = out0 + ((size_t)gb * kT + t) * kVC;
#pragma unroll
  for (int i = 0; i < 8; i++) { int c = tid + i * 256; if (c < kVC) orow[c] = xv[i] - lse; }
  if (tid == 0) {
    tok[b] = nt;
    int tg = targets[(size_t)gb * kT + t];
    float mk = mask[(size_t)gb * kT + t];
    atomicAdd(loss, (lse - lrow[tg]) * mk * (1.f / 16384.f));  // /B /T
  }
  const float* hrow = hr + (size_t)np * BC * kH + (size_t)b * kH;
  for (int k = tid; k < kH; k += 256) hsh[k] = hrow[k];
  __syncthreads();
  const float* A = Atab + (size_t)nt * kH;
  for (int j = tid; j < kH; j += 256) {
    const float* row = aW + (size_t)j * 1024 + 512;
    float acc = A[j];
    for (int k = 0; k < kH; k += 4) {
      float4 f = *(const float4*)(row + k);
      acc += hsh[k] * f.x + hsh[k + 1] * f.y + hsh[k + 2] * f.z + hsh[k + 3] * f.w;
    }
    key[(size_t)b * kH + j] = acc;
  }
  __syncthreads();   // shared reuse guard
}

// ======================= persistent cooperative kernels ====================

// Encoder: grid 2*BC blocks x 256. Whh rows for this block's units cached in
// LDS (values bit-identical; dot order identical to per-step kernel).
__global__ __launch_bounds__(256, 1)
void k_enc_persist(const int* tokens, const float* Whf, const float* Whb,
                   const float* bhhf, const float* bhhb, const float* gi,
                   float* henc, float* enc, int BC, int lbc, int b0) {
  cg::grid_group grid = cg::this_grid();
  extern __shared__ float wlds[];
  int d = blockIdx.x >> lbc;
  int blk = blockIdx.x & (BC - 1);
  int b = threadIdx.x & (BC - 1), q = threadIdx.x >> lbc;
  int nu = 256 >> lbc;
  int u = blk * nu + q;
  const float* Whh = d ? Whb : Whf;
  const float* bhh = d ? bhhb : bhhf;
  bool useLds = ((size_t)3 * nu * kH2 * 4 <= 48 * 1024);
  const float *wr, *wz, *wn;
  if (useLds) {
    int q4 = kH2 / 4;
    int tot4 = 3 * nu * q4;
    for (int i4 = threadIdx.x; i4 < tot4; i4 += 256) {
      int r = i4 / q4;
      int k4 = i4 - r * q4;
      int g = r / nu, qq = r - g * nu;
      *(float4*)(wlds + (size_t)r * kH2 + k4 * 4) =
          *(const float4*)(Whh + (size_t)(g * kH2 + blk * nu + qq) * kH2 + k4 * 4);
    }
    __syncthreads();
    wr = wlds + (size_t)(0 * nu + q) * kH2;
    wz = wlds + (size_t)(1 * nu + q) * kH2;
    wn = wlds + (size_t)(2 * nu + q) * kH2;
  } else {
    wr = Whh + (size_t)(0 * kH2 + u) * kH2;
    wz = Whh + (size_t)(1 * kH2 + u) * kH2;
    wn = Whh + (size_t)(2 * kH2 + u) * kH2;
  }
  float br = bhh[u], bz = bhh[kH2 + u], bn = bhh[2 * kH2 + u];
  const int* myTok = tokens + (size_t)(b0 + b) * kLIN;
  for (int t = 0; t < kLIN; ++t) {
    int pp = t & 1;
    const float* hin = henc + (size_t)(pp * 2 + d) * kH2 * BC;
    float* hout = henc + (size_t)((1 - pp) * 2 + d) * kH2 * BC;
    float ar = br, az = bz, an = bn;
    for (int k = 0; k < kH2; k += 4) {
      float4 fr = *(const float4*)(wr + k);
      float4 fz = *(const float4*)(wz + k);
      float4 fn = *(const float4*)(wn + k);
      float h0v = hin[(k + 0) * BC + b], h1v = hin[(k + 1) * BC + b];
      float h2v = hin[(k + 2) * BC + b], h3v = hin[(k + 3) * BC + b];
      ar += h0v * fr.x + h1v * fr.y + h2v * fr.z + h3v * fr.w;
      az += h0v * fz.x + h1v * fz.y + h2v * fz.z + h3v * fz.w;
      an += h0v * fn.x + h1v * fn.y + h2v * fn.z + h3v * fn.w;
    }
    int v = myTok[t];
    const float* git = gi + (size_t)(v * 2 + d) * 768;
    float r = 1.f / (1.f + expf(-(git[u] + ar)));
    float z = 1.f / (1.f + expf(-(git[kH2 + u] + az)));
    float n = tanhf(git[2 * kH2 + u] + r * an);
    float hprev = hin[(size_t)u * BC + b];
    float hnew = (1.f - z) * n + z * hprev;
    hout[(size_t)u * BC + b] = hnew;
    enc[((size_t)b * kLIN + t) * kH + d * kH2 + u] = hnew;
    grid.sync();
  }
}

// Decoder: any grid size (block-stride over phase work items), 5 grid.syncs
// per timestep. Phase bodies identical to the per-step kernels.
__global__ __launch_bounds__(256, 2)
void k_dec_persist(const float* encAll, const float* cW, const float* Ctab,
                   const float* dWi, const float* dWh, const float* dbi, const float* dbh,
                   const float* oW, const float* ob, const float* aW, const float* Atab,
                   const int* targets, const float* mask,
                   float* key, float* sc, float* pm, float* pd, float* pctx,
                   float* gt, float* ht, float* hr, float* lg,
                   int* tok, float* loss, float* out0, float* out1,
                   int BC, int lbc, int b0) {
  cg::grid_group grid = cg::this_grid();
  int tid = threadIdx.x;
  int G = gridDim.x;
  for (int t = 0; t < kT; ++t) {
    int pp = t & 1, np = 1 - pp;
    for (int wk = blockIdx.x; wk < BC * 8; wk += G)
      phaseA(wk >> 3, wk & 7, tid, encAll, key, sc, pm, pd, pctx);
    grid.sync();
    for (int wk = blockIdx.x; wk < BC; wk += G)
      phaseB(wk, tid, cW, Ctab, sc, pm, pd, pctx, tok, out1, gt, BC, b0, t);
    grid.sync();
    for (int wk = blockIdx.x; wk < 2 * BC; wk += G)
      phaseC(wk, tid, dWi, dWh, dbi, dbh, gt, ht, hr, BC, lbc, pp);
    grid.sync();
    for (int wk = blockIdx.x; wk < BC * 8; wk += G)
      phaseD(wk >> 3, wk & 7, tid, oW, ob, hr, lg, BC, np);
    grid.sync();
    for (int wk = blockIdx.x; wk < BC; wk += G)
      phaseE(wk, tid, aW, targets, mask, Atab, hr, lg, key, tok, loss,
             out0, BC, b0, t, np);
    grid.sync();
  }
}

// ======================= fallback per-step kernels =========================

__global__ __launch_bounds__(256)
void k_enc_step(const int* tokens, const float* Whf, const float* Whb,
                const float* bhhf, const float* bhhb, const float* gi,
                float* henc, float* enc, int t, int pp, int BC, int lbc, int b0) {
  int d = blockIdx.x >> lbc;
  int blk = blockIdx.x & (BC - 1);
  int b = threadIdx.x & (BC - 1), q = threadIdx.x >> lbc;
  int u = blk * (256 >> lbc) + q;
  const float* Whh = d ? Whb : Whf;
  const float* bhh = d ? bhhb : bhhf;
  const float* hin = henc + (size_t)(pp * 2 + d) * kH2 * BC;
  float* hout = henc + (size_t)((1 - pp) * 2 + d) * kH2 * BC;
  const float* wr = Whh + (size_t)(0 * kH2 + u) * kH2;
  const float* wz = Whh + (size_t)(1 * kH2 + u) * kH2;
  const float* wn = Whh + (size_t)(2 * kH2 + u) * kH2;
  float ar = bhh[u], az = bhh[kH2 + u], an = bhh[2 * kH2 + u];
  for (int k = 0; k < kH2; k += 4) {
    float4 fr = *(const float4*)(wr + k);
    float4 fz = *(const float4*)(wz + k);
    float4 fn = *(const float4*)(wn + k);
    float h0v = hin[(k + 0) * BC + b], h1v = hin[(k + 1) * BC + b];
    float h2v = hin[(k + 2) * BC + b], h3v = hin[(k + 3) * BC + b];
    ar += h0v * fr.x + h1v * fr.y + h2v * fr.z + h3v * fr.w;
    az += h0v * fz.x + h1v * fz.y + h2v * fz.z + h3v * fz.w;
    an += h0v * fn.x + h1v * fn.y + h2v * fn.z + h3v * fn.w;
  }
  int v = tokens[(size_t)(b0 + b) * kLIN + t];
  const float* git = gi + (size_t)(v * 2 + d) * 768;
  float r = 1.f / (1.f + expf(-(git[u] + ar)));
  float z = 1.f / (1.f + expf(-(git[kH2 + u] + az)));
  float n = tanhf(git[2 * kH2 + u] + r * an);
  float hprev = hin[(size_t)u * BC + b];
  float hnew = (1.f - z) * n + z * hprev;
  hout[(size_t)u * BC + b] = hnew;
  enc[((size_t)b * kLIN + t) * kH + d * kH2 + u] = hnew;
}

__global__ __launch_bounds__(256)
void k_scores(const float* encAll, const float* keyAll, float* sc,
              float* pm, float* pd, float* pctx) {
  phaseA(blockIdx.x >> 3, blockIdx.x & 7, threadIdx.x, encAll, keyAll, sc, pm, pd, pctx);
}

__global__ __launch_bounds__(256)
void k_ctx_g(const float* cW, const float* Ctab, const float* sc,
             const float* pm, const float* pd, const float* pctx,
             const int* tok, float* out1, float* gt, int BC, int b0, int t) {
  phaseB(blockIdx.x, threadIdx.x, cW, Ctab, sc, pm, pd, pctx, tok, out1, gt, BC, b0, t);
}

__global__ __launch_bounds__(256)
void k_gru(const float* Wih, const float* Whh, const float* bih, const float* bhh,
           const float* gt, float* ht, float* hr, int BC, int lbc, int pp) {
  phaseC(blockIdx.x, threadIdx.x, Wih, Whh, bih, bhh, gt, ht, hr, BC, lbc, pp);
}

__global__ __launch_bounds__(256)
void k_logits(const float* oW, const float* ob, const float* hr, float* lg,
              int BC, int np) {
  phaseD(blockIdx.x >> 3, blockIdx.x & 7, threadIdx.x, oW, ob, hr, lg, BC, np);
}

__global__ __launch_bounds__(256)
void k_finish(const float* aW, const int* targets, const float* mask,
              const float* Atab, const float* hr, const float* lg,
              float* key, int* tok, float* loss, float* out0,
              int BC, int b0, int t, int np) {
  phaseE(blockIdx.x, threadIdx.x, aW, targets, mask, Atab, hr, lg, key, tok,
         loss, out0, BC, b0, t, np);
}

// ----------------------------------------------------- decoder prologue
__global__ __launch_bounds__(256)
void k_prologue(const float* enc, const float* Atab, const float* aW,
                float* hr, float* ht, float* key, int* tok, int BC) {
  int b = blockIdx.x, tid = threadIdx.x;
  __shared__ float h[kH];
  const float* h0 = enc + ((size_t)b * kLIN + (kLIN - 1)) * kH;
  for (int k = tid; k < kH; k += 256) {
    float v = h0[k];
    h[k] = v;
    hr[(size_t)b * kH + k] = v;
    ht[(size_t)k * BC + b] = v;
  }
  if (tid == 0) tok[b] = kSTART;
  __syncthreads();
  const float* A = Atab + (size_t)kSTART * kH;
  for (int j = tid; j < kH; j += 256) {
    const float* row = aW + (size_t)j * 1024 + 512;
    float acc = A[j];
    for (int k = 0; k < kH; k += 4) {
      float4 f = *(const float4*)(row + k);
      acc += h[k] * f.x + h[k + 1] * f.y + h[k + 2] * f.z + h[k + 3] * f.w;
    }
    key[(size_t)b * kH + j] = acc;
  }
}

__global__ void k_loss_out(float* dst, const float* loss) {
  if (threadIdx.x == 0 && blockIdx.x == 0) *dst = *loss;
}

// ---------------------------------------------------------------------------
static int g_coop = -1;      // -1 unknown, 1 works, 0 rejected -> fallback
static int g_dec_grid = 0;   // cached co-residency-safe decoder grid

extern "C" void kernel_launch(void* const* d_in, const int* in_sizes, int n_in,
                              void* d_out, int out_size, void* d_ws, size_t ws_size,
                              hipStream_t stream) {
  (void)in_sizes; (void)n_in;
  const int*   tok_in = (const int*)d_in[0];
  const int*   tgt    = (const int*)d_in[1];
  const float* mask   = (const float*)d_in[2];
  const float* emb_j  = (const float*)d_in[3];
  const float* emb_c  = (const float*)d_in[4];
  const float* eWif   = (const float*)d_in[5];
  const float* eWhf   = (const float*)d_in[6];
  const float* ebif   = (const float*)d_in[7];
  const float* ebhf   = (const float*)d_in[8];
  const float* eWib   = (const float*)d_in[9];
  const float* eWhb   = (const float*)d_in[10];
  const float* ebib   = (const float*)d_in[11];
  const float* ebhb   = (const float*)d_in[12];
  const float* dWi    = (const float*)d_in[13];
  const float* dWh    = (const float*)d_in[14];
  const float* dbi    = (const float*)d_in[15];
  const float* dbh    = (const float*)d_in[16];
  const float* aW     = (const float*)d_in[17];
  const float* ab     = (const float*)d_in[18];
  const float* cW     = (const float*)d_in[19];
  const float* cb     = (const float*)d_in[20];
  const float* oW     = (const float*)d_in[21];
  const float* ob     = (const float*)d_in[22];
  float* ws   = (float*)d_ws;
  float* out0 = (float*)d_out;
  float* out1 = out0 + (size_t)kB * kT * kVC;

  // ---- workspace layout (floats); small state sized for BC=64 capacity
  const size_t GI = 0;
  const size_t A  = GI + 107520;            // 70*2*768
  const size_t C  = A + 1024000;            // 2000*512
  const size_t SMALL = C + 1024000;
  size_t o = SMALL;
  const size_t HENC = o; o += 4 * 256 * 64; // [2pp][2dir][256][BC]
  const size_t KEY  = o; o += 64 * 512;
  const size_t SC   = o; o += 64 * 1024;
  const size_t PM   = o; o += 512;
  const size_t PD   = o; o += 512;
  const size_t PCT  = o; o += 64 * 8 * 512;
  const size_t GT   = o; o += 512 * 64;
  const size_t HR   = o; o += 2 * 64 * 512;
  const size_t HT   = o; o += 2 * 512 * 64;
  const size_t LG   = o; o += 64 * 2000;
  const size_t TOKo = o; o += 64;
  const size_t LOSS = o; o += 1;
  const size_t ENC  = o;                    // + BC*1024*512
  const int small_n = (int)(ENC - SMALL);

  int BC = 64;
  while (BC > 8 && (ENC + (size_t)BC * kLIN * kH) * sizeof(float) > ws_size) BC >>= 1;
  int lbc = (BC == 64) ? 6 : (BC == 32) ? 5 : (BC == 16) ? 4 : 3;
  int NC = kB / BC;
  int nu = 256 >> lbc;
  size_t wbytes = (size_t)3 * nu * kH2 * 4;
  unsigned enc_smem = (wbytes <= 48 * 1024) ? (unsigned)wbytes : 0u;

  float* gi_p   = ws + GI;
  float* A_p    = ws + A;
  float* C_p    = ws + C;
  float* henc_p = ws + HENC;
  float* key_p  = ws + KEY;
  float* sc_p   = ws + SC;
  float* pm_p   = ws + PM;
  float* pd_p   = ws + PD;
  float* pct_p  = ws + PCT;
  float* gt_p   = ws + GT;
  float* hr_p   = ws + HR;
  float* ht_p   = ws + HT;
  float* lg_p   = ws + LG;
  float* loss_p = ws + LOSS;
  float* enc_p  = ws + ENC;
  int* tokp = (int*)(ws + TOKo);

  // co-residency-safe decoder grid (cached; host-only query, capture-safe)
  if (g_dec_grid == 0) {
    int ma = 0;
    hipError_t oe = hipOccupancyMaxActiveBlocksPerMultiprocessor(
        &ma, reinterpret_cast<const void*>(&k_dec_persist), 256, (size_t)0);
    if (oe != hipSuccess || ma < 1) { ma = 1; (void)hipGetLastError(); }
    long g = (long)ma * 256;              // 256 CUs on MI355X
    if (g > 512) g = 512;
    g_dec_grid = (int)g;
  }
  int decGrid = g_dec_grid;
  if (decGrid > BC * 8) decGrid = BC * 8;

  k_zero<<<(small_n + 255) / 256, 256, 0, stream>>>(ws + SMALL, small_n);
  k_gi_table<<<140, 256, 0, stream>>>(emb_j, eWif, eWib, ebif, ebib, gi_p);
  k_ac_emb<<<2000, 256, 0, stream>>>(emb_c, aW, ab, cW, cb, A_p, C_p);

  for (int c = 0; c < NC; c++) {
    int b0 = c * BC;
    k_zero<<<(4 * 256 * BC + 255) / 256, 256, 0, stream>>>(henc_p, 4 * 256 * BC);

    // ---------------- encoder: cooperative, else per-step fallback
    bool enc_done = false;
    if (g_coop != 0) {
      void* eargs[] = {(void*)&tok_in, (void*)&eWhf, (void*)&eWhb, (void*)&ebhf,
                       (void*)&ebhb, (void*)&gi_p, (void*)&henc_p, (void*)&enc_p,
                       (void*)&BC, (void*)&lbc, (void*)&b0};
      hipError_t e = hipLaunchCooperativeKernel(
          reinterpret_cast<void*>(k_enc_persist), dim3(2 * BC), dim3(256),
          eargs, enc_smem, stream);
      if (e == hipSuccess) { enc_done = true; if (g_coop < 0) g_coop = 1; }
      else { g_coop = 0; (void)hipGetLastError(); }
    }
    if (!enc_done) {
      for (int t = 0; t < kLIN; t++)
        k_enc_step<<<2 * BC, 256, 0, stream>>>(tok_in, eWhf, eWhb, ebhf, ebhb,
                                               gi_p, henc_p, enc_p,
                                               t, t & 1, BC, lbc, b0);
    }

    k_prologue<<<BC, 256, 0, stream>>>(enc_p, A_p, aW, hr_p, ht_p, key_p, tokp, BC);

    // ---------------- decoder: cooperative, else per-step fallback
    bool dec_done = false;
    if (g_coop != 0) {
      void* dargs[] = {(void*)&enc_p, (void*)&cW, (void*)&C_p, (void*)&dWi,
                       (void*)&dWh, (void*)&dbi, (void*)&dbh, (void*)&oW,
                       (void*)&ob, (void*)&aW, (void*)&A_p, (void*)&tgt,
                       (void*)&mask, (void*)&key_p, (void*)&sc_p, (void*)&pm_p,
                       (void*)&pd_p, (void*)&pct_p, (void*)&gt_p, (void*)&ht_p,
                       (void*)&hr_p, (void*)&lg_p, (void*)&tokp, (void*)&loss_p,
                       (void*)&out0, (void*)&out1, (void*)&BC, (void*)&lbc,
                       (void*)&b0};
      hipError_t e = hipLaunchCooperativeKernel(
          reinterpret_cast<void*>(k_dec_persist), dim3(decGrid), dim3(256),
          dargs, 0, stream);
      if (e == hipSuccess) { dec_done = true; if (g_coop < 0) g_coop = 1; }
      else { g_coop = 0; (void)hipGetLastError(); }
    }
    if (!dec_done) {
      for (int t = 0; t < kT; t++) {
        int pp = t & 1, np = 1 - pp;
        k_scores<<<BC * 8, 256, 0, stream>>>(enc_p, key_p, sc_p, pm_p, pd_p, pct_p);
        k_ctx_g<<<BC, 256, 0, stream>>>(cW, C_p, sc_p, pm_p, pd_p, pct_p,
                                        tokp, out1, gt_p, BC, b0, t);
        k_gru<<<2 * BC, 256, 0, stream>>>(dWi, dWh, dbi, dbh, gt_p,
                                          ht_p, hr_p, BC, lbc, pp);
        k_logits<<<BC * 8, 256, 0, stream>>>(oW, ob, hr_p, lg_p, BC, np);
        k_finish<<<BC, 256, 0, stream>>>(aW, tgt, mask, A_p, hr_p, lg_p,
                                         key_p, tokp, loss_p, out0,
                                         BC, b0, t, np);
      }
    }
  }
  k_loss_out<<<1, 64, 0, stream>>>(out0 + (size_t)out_size - 1, loss_p);
}

// Round 4
// 116984.607 us; speedup vs baseline: 1.1587x; 1.1587x over previous
//
#include <hip/hip_runtime.h>
#include <hip/hip_cooperative_groups.h>
#include <cstdint>
#include <cstddef>

namespace cg = cooperative_groups;

// ---------------------------------------------------------------------------
// Seq2SeqNet: bidir GRU encoder (1024 steps) + attention GRU greedy decoder
// (256 steps). ALL math fp32, phase arithmetic bit-identical to the verified
// multi-launch kernel (greedy argmax feedback: ANY reassociation can flip a
// token). Persistent cooperative kernels kill launch overhead; decoder grid
// is capped at 128 blocks because ROCm grid.sync cost explodes with block
// count (measured: ~6us @128 blocks, ~95us @512 blocks). PhaseA/D are
// ILP-restructured (loads hoisted, reduction order unchanged) so 4 serial
// work items per block stay cheap. Multi-launch fallback kept.
// [Resubmission of round-3 kernel: round-3 bench was an infra failure
//  ("container failed twice"), not a kernel verdict.]
// ---------------------------------------------------------------------------

constexpr int kH = 512, kH2 = 256, kVC = 2000, kB = 64, kLIN = 1024, kT = 256;
constexpr int kSTART = 1;

// -------------------------------------------------------------------- zero
__global__ __launch_bounds__(256) void k_zero(float* p, int n) {
  int i = blockIdx.x * 256 + threadIdx.x;
  if (i < n) p[i] = 0.f;
}

// ------------------------------------------- encoder input-gate token table
__global__ __launch_bounds__(256)
void k_gi_table(const float* emb_jamo, const float* Wf, const float* Wb,
                const float* bihf, const float* bihb, float* gi) {
  int v = blockIdx.x >> 1, d = blockIdx.x & 1;
  const float* W = d ? Wb : Wf;
  const float* bih = d ? bihb : bihf;
  __shared__ float x[kH];
  for (int k = threadIdx.x; k < kH; k += 256) x[k] = emb_jamo[v * kH + k];
  __syncthreads();
  for (int j = threadIdx.x; j < 3 * kH2; j += 256) {
    float acc = bih[j];
    const float* row = W + (size_t)j * kH;
    for (int k = 0; k < kH; k += 4) {
      float4 f = *(const float4*)(row + k);
      acc += x[k] * f.x + x[k + 1] * f.y + x[k + 2] * f.z + x[k + 3] * f.w;
    }
    gi[(size_t)(v * 2 + d) * 768 + j] = acc;
  }
}

// ------------------ decoder embedding tables (bias folded)
__global__ __launch_bounds__(256)
void k_ac_emb(const float* emb_char, const float* attn_W, const float* attn_b,
              const float* comb_W, const float* comb_b, float* A, float* C) {
  int v = blockIdx.x;
  __shared__ float x[kH];
  for (int k = threadIdx.x; k < kH; k += 256) x[k] = emb_char[v * kH + k];
  __syncthreads();
  for (int j = threadIdx.x; j < kH; j += 256) {
    float a = attn_b[j], c = comb_b[j];
    const float* ra = attn_W + (size_t)j * 1024;
    const float* rc = comb_W + (size_t)j * 1024;
    for (int k = 0; k < kH; k += 4) {
      float4 fa = *(const float4*)(ra + k), fc = *(const float4*)(rc + k);
      a += x[k] * fa.x + x[k + 1] * fa.y + x[k + 2] * fa.z + x[k + 3] * fa.w;
      c += x[k] * fc.x + x[k + 1] * fc.y + x[k + 2] * fc.z + x[k + 3] * fc.w;
    }
    A[(size_t)v * kH + j] = a;
    C[(size_t)v * kH + j] = c;
  }
}

// ======================= decoder phase bodies ==============================
// Arithmetic order identical to the verified kernel; only load scheduling
// (ILP batching) differs.

// Phase A: scores + per-tile softmax partials + per-tile ctx partials.
__device__ void phaseA(int b, int lt, int tid, const float* encAll,
                       const float* keyAll, float* sc, float* pm, float* pd,
                       float* pctx) {
  int lane = tid & 63, w = tid >> 6, hl = lane & 31, half = lane >> 5;
  __shared__ float s_tile[128], e_tile[128], red[128];
  const float* enc = encAll + (size_t)b * kLIN * kH;
  float kreg[16];
  const float* key = keyAll + (size_t)b * kH + hl * 16;
#pragma unroll
  for (int m = 0; m < 16; m += 4) *(float4*)(kreg + m) = *(const float4*)(key + m);
  // score pass: 4 rows batched -> 16 float4 loads in flight per batch.
  for (int i0 = 0; i0 < 16; i0 += 4) {
    float4 v[4][4];
#pragma unroll
    for (int j = 0; j < 4; j++) {
      int ll = w * 32 + (i0 + j) * 2 + half;
      const float* row = enc + (size_t)(lt * 128 + ll) * kH + hl * 16;
#pragma unroll
      for (int m = 0; m < 4; m++) v[j][m] = *(const float4*)(row + m * 4);
    }
#pragma unroll
    for (int j = 0; j < 4; j++) {
      int ll = w * 32 + (i0 + j) * 2 + half;
      int l = lt * 128 + ll;
      float acc = 0.f;
#pragma unroll
      for (int m = 0; m < 4; m++) {
        acc += v[j][m].x * kreg[4 * m] + v[j][m].y * kreg[4 * m + 1] +
               v[j][m].z * kreg[4 * m + 2] + v[j][m].w * kreg[4 * m + 3];
      }
#pragma unroll
      for (int m2 = 16; m2 > 0; m2 >>= 1) acc += __shfl_xor(acc, m2, 32);
      if (hl == 0) { s_tile[ll] = acc; sc[(size_t)b * kLIN + l] = acc; }
    }
  }
  __syncthreads();
  if (tid < 128) red[tid] = s_tile[tid];
  __syncthreads();
  for (int s = 64; s > 0; s >>= 1) {
    if (tid < s) red[tid] = fmaxf(red[tid], red[tid + s]);
    __syncthreads();
  }
  float mt = red[0];
  __syncthreads();
  if (tid < 128) { e_tile[tid] = expf(s_tile[tid] - mt); red[tid] = e_tile[tid]; }
  __syncthreads();
  for (int s = 64; s > 0; s >>= 1) {
    if (tid < s) red[tid] += red[tid + s];
    __syncthreads();
  }
  float dt = red[0];
  int h0i = tid * 2;
  float cx = 0.f, cy = 0.f;
  const float* base = enc + (size_t)(lt * 128) * kH + h0i;
  // ctx pass: loads hoisted 4 at a time; accumulation order unchanged.
  for (int l0 = 0; l0 < 128; l0 += 4) {
    float2 v0 = *(const float2*)(base + (size_t)(l0 + 0) * kH);
    float2 v1 = *(const float2*)(base + (size_t)(l0 + 1) * kH);
    float2 v2 = *(const float2*)(base + (size_t)(l0 + 2) * kH);
    float2 v3 = *(const float2*)(base + (size_t)(l0 + 3) * kH);
    float e0 = e_tile[l0], e1 = e_tile[l0 + 1], e2 = e_tile[l0 + 2], e3 = e_tile[l0 + 3];
    cx += e0 * v0.x; cy += e0 * v0.y;
    cx += e1 * v1.x; cy += e1 * v1.y;
    cx += e2 * v2.x; cy += e2 * v2.y;
    cx += e3 * v3.x; cy += e3 * v3.y;
  }
  float* pc = pctx + ((size_t)b * 8 + lt) * kH;
  pc[h0i] = cx; pc[h0i + 1] = cy;
  if (tid == 0) { pm[b * 8 + lt] = mt; pd[b * 8 + lt] = dt; }
  __syncthreads();   // shared reuse guard (no numeric effect)
}

// Phase B: combine tile partials -> ctx, attention weights, g = relu(...)
__device__ void phaseB(int b, int tid, const float* cW, const float* Ctab,
                       const float* sc, const float* pm, const float* pd,
                       const float* pctx, const int* tok, float* out1,
                       float* gt, int BC, int b0, int t) {
  __shared__ float f8[8], MD[2], ctxl[kH];
  __shared__ int tokl;
  if (tid == 0) {
    float M = -1e30f;
    for (int i = 0; i < 8; i++) M = fmaxf(M, pm[b * 8 + i]);
    float D = 0.f;
    for (int i = 0; i < 8; i++) {
      float f = expf(pm[b * 8 + i] - M);
      f8[i] = f; D += f * pd[b * 8 + i];
    }
    MD[0] = M; MD[1] = 1.f / D;
    tokl = tok[b];
  }
  __syncthreads();
  float M = MD[0], invD = MD[1];
  int h0i = tid * 2;
  float cx = 0.f, cy = 0.f;
  for (int i = 0; i < 8; i++) {
    const float* pc = pctx + ((size_t)b * 8 + i) * kH + h0i;
    cx += f8[i] * pc[0]; cy += f8[i] * pc[1];
  }
  ctxl[h0i] = cx * invD; ctxl[h0i + 1] = cy * invD;
  int gb = b0 + b;
  for (int l = tid; l < kLIN; l += 256)
    out1[((size_t)gb * kLIN + l) * kT + t] = expf(sc[(size_t)b * kLIN + l] - M) * invD;
  __syncthreads();
  int tk = tokl;
  for (int j = tid; j < kH; j += 256) {
    const float* row = cW + (size_t)j * 1024 + 512;
    float acc = Ctab[(size_t)tk * kH + j];
    for (int k = 0; k < kH; k += 4) {
      float4 f = *(const float4*)(row + k);
      acc += ctxl[k] * f.x + ctxl[k + 1] * f.y + ctxl[k + 2] * f.z + ctxl[k + 3] * f.w;
    }
    gt[(size_t)j * BC + b] = fmaxf(acc, 0.f);
  }
  __syncthreads();   // shared reuse guard
}

// Phase C: decoder GRU, thread per (u, b)
__device__ void phaseC(int blk, int tid, const float* Wih, const float* Whh,
                       const float* bih, const float* bhh, const float* gt,
                       float* ht, float* hr, int BC, int lbc, int pp) {
  int b = tid & (BC - 1), q = tid >> lbc;
  int u = blk * (256 >> lbc) + q;
  const float* htp = ht + (size_t)pp * kH * BC;
  float air = bih[u], aiz = bih[kH + u], ain = bih[2 * kH + u];
  float ahr = bhh[u], ahz = bhh[kH + u], ahn = bhh[2 * kH + u];
  const float* wir = Wih + (size_t)(0 * kH + u) * kH;
  const float* wiz = Wih + (size_t)(1 * kH + u) * kH;
  const float* win = Wih + (size_t)(2 * kH + u) * kH;
  const float* whr = Whh + (size_t)(0 * kH + u) * kH;
  const float* whz = Whh + (size_t)(1 * kH + u) * kH;
  const float* whn = Whh + (size_t)(2 * kH + u) * kH;
  for (int k = 0; k < kH; k += 4) {
    float4 fir = *(const float4*)(wir + k), fiz = *(const float4*)(wiz + k), fin = *(const float4*)(win + k);
    float4 fhr = *(const float4*)(whr + k), fhz = *(const float4*)(whz + k), fhn = *(const float4*)(whn + k);
    float g0 = gt[(k + 0) * BC + b], g1 = gt[(k + 1) * BC + b];
    float g2 = gt[(k + 2) * BC + b], g3 = gt[(k + 3) * BC + b];
    float h0v = htp[(k + 0) * BC + b], h1v = htp[(k + 1) * BC + b];
    float h2v = htp[(k + 2) * BC + b], h3v = htp[(k + 3) * BC + b];
    air += g0 * fir.x + g1 * fir.y + g2 * fir.z + g3 * fir.w;
    aiz += g0 * fiz.x + g1 * fiz.y + g2 * fiz.z + g3 * fiz.w;
    ain += g0 * fin.x + g1 * fin.y + g2 * fin.z + g3 * fin.w;
    ahr += h0v * fhr.x + h1v * fhr.y + h2v * fhr.z + h3v * fhr.w;
    ahz += h0v * fhz.x + h1v * fhz.y + h2v * fhz.z + h3v * fhz.w;
    ahn += h0v * fhn.x + h1v * fhn.y + h2v * fhn.z + h3v * fhn.w;
  }
  float r = 1.f / (1.f + expf(-(air + ahr)));
  float z = 1.f / (1.f + expf(-(aiz + ahz)));
  float n = tanhf(ain + r * ahn);
  float hp = htp[(size_t)u * BC + b];
  float hnew = (1.f - z) * n + z * hp;
  ht[(size_t)(1 - pp) * kH * BC + (size_t)u * BC + b] = hnew;
  hr[(size_t)(1 - pp) * BC * kH + (size_t)b * kH + u] = hnew;
}

// Phase D: logits for one (b, c-tile of 250). Loads hoisted pairwise with a
// clamped row index; dot/shfl order and store guard unchanged.
__device__ void phaseD(int b, int ct, int tid, const float* oW, const float* ob,
                       const float* hr, float* lg, int BC, int np) {
  int lane = tid & 63, w = tid >> 6, hl = lane & 31, half = lane >> 5;
  const float* hrow = hr + (size_t)np * BC * kH + (size_t)b * kH + hl * 16;
  float hreg[16];
#pragma unroll
  for (int m = 0; m < 16; m += 4) *(float4*)(hreg + m) = *(const float4*)(hrow + m);
  int c0 = ct * 250;
  for (int i0 = 0; i0 < 32; i0 += 2) {
    int ca = c0 + (i0 + 0) * 8 + w * 2 + half;
    int cb = c0 + (i0 + 1) * 8 + w * 2 + half;
    int cca = ca < kVC ? ca : kVC - 1;
    int ccb = cb < kVC ? cb : kVC - 1;
    float4 va[4], vb[4];
    const float* rowa = oW + (size_t)cca * kH + hl * 16;
    const float* rowb = oW + (size_t)ccb * kH + hl * 16;
#pragma unroll
    for (int m = 0; m < 4; m++) { va[m] = *(const float4*)(rowa + m * 4); vb[m] = *(const float4*)(rowb + m * 4); }
    float acca = 0.f, accb = 0.f;
#pragma unroll
    for (int m = 0; m < 4; m++) {
      acca += va[m].x * hreg[4 * m] + va[m].y * hreg[4 * m + 1] +
              va[m].z * hreg[4 * m + 2] + va[m].w * hreg[4 * m + 3];
    }
#pragma unroll
    for (int m = 0; m < 4; m++) {
      accb += vb[m].x * hreg[4 * m] + vb[m].y * hreg[4 * m + 1] +
              vb[m].z * hreg[4 * m + 2] + vb[m].w * hreg[4 * m + 3];
    }
#pragma unroll
    for (int m2 = 16; m2 > 0; m2 >>= 1) acca += __shfl_xor(acca, m2, 32);
#pragma unroll
    for (int m2 = 16; m2 > 0; m2 >>= 1) accb += __shfl_xor(accb, m2, 32);
    if (ca < c0 + 250 && hl == 0) lg[(size_t)b * kVC + ca] = acca + ob[ca];
    if (cb < c0 + 250 && hl == 0) lg[(size_t)b * kVC + cb] = accb + ob[cb];
  }
}

// Phase E: log_softmax + out0 + argmax + loss + next-step key
__device__ void phaseE(int b, int tid, const float* aW, const int* targets,
                       const float* mask, const float* Atab, const float* hr,
                       const float* lg, float* key, int* tok, float* loss,
                       float* out0, int BC, int b0, int t, int np) {
  int gb = b0 + b;
  __shared__ float rv[256]; __shared__ int ri[256]; __shared__ float rs[256];
  __shared__ float hsh[kH];
  const float* lrow = lg + (size_t)b * kVC;
  float xv[8];
  float bv = -3.4e38f; int bi = kVC;
#pragma unroll
  for (int i = 0; i < 8; i++) {
    int c = tid + i * 256;
    float x = (c < kVC) ? lrow[c] : -3.4e38f;
    xv[i] = x;
    if (x > bv) { bv = x; bi = c; }
  }
  rv[tid] = bv; ri[tid] = bi;
  __syncthreads();
  for (int s = 128; s > 0; s >>= 1) {
    if (tid < s) {
      float v2 = rv[tid + s]; int i2 = ri[tid + s];
      if (v2 > rv[tid] || (v2 == rv[tid] && i2 < ri[tid])) { rv[tid] = v2; ri[tid] = i2; }
    }
    __syncthreads();
  }
  float M = rv[0]; int nt = ri[0];
  float se = 0.f;
#pragma unroll
  for (int i = 0; i < 8; i++) { int c = tid + i * 256; if (c < kVC) se += expf(xv[i] - M); }
  rs[tid] = se;
  __syncthreads();
  for (int s = 128; s > 0; s >>= 1) {
    if (tid < s) rs[tid] += rs[tid + s];
    __syncthreads();
  }
  float lse = M + logf(rs[0]);
  float* orow = out0 + ((size_t)gb * kT + t) * kVC;
#pragma unroll
  for (int i = 0; i < 8; i++) { int c = tid + i * 256; if (c < kVC) orow[c] = xv[i] - lse; }
  if (tid == 0) {
    tok[b] = nt;
    int tg = targets[(size_t)gb * kT + t];
    float mk = mask[(size_t)gb * kT + t];
    atomicAdd(loss, (lse - lrow[tg]) * mk * (1.f / 16384.f));  // /B /T
  }
  const float* hrow = hr + (size_t)np * BC * kH + (size_t)b * kH;
  for (int k = tid; k < kH; k += 256) hsh[k] = hrow[k];
  __syncthreads();
  const float* A = Atab + (size_t)nt * kH;
  for (int j = tid; j < kH; j += 256) {
    const float* row = aW + (size_t)j * 1024 + 512;
    float acc = A[j];
    for (int k = 0; k < kH; k += 4) {
      float4 f = *(const float4*)(row + k);
      acc += hsh[k] * f.x + hsh[k + 1] * f.y + hsh[k + 2] * f.z + hsh[k + 3] * f.w;
    }
    key[(size_t)b * kH + j] = acc;
  }
  __syncthreads();   // shared reuse guard
}

// ======================= persistent cooperative kernels ====================

// Encoder: grid 2*BC blocks x 256. Whh rows cached in LDS.
__global__ __launch_bounds__(256, 1)
void k_enc_persist(const int* tokens, const float* Whf, const float* Whb,
                   const float* bhhf, const float* bhhb, const float* gi,
                   float* henc, float* enc, int BC, int lbc, int b0) {
  cg::grid_group grid = cg::this_grid();
  extern __shared__ float wlds[];
  int d = blockIdx.x >> lbc;
  int blk = blockIdx.x & (BC - 1);
  int b = threadIdx.x & (BC - 1), q = threadIdx.x >> lbc;
  int nu = 256 >> lbc;
  int u = blk * nu + q;
  const float* Whh = d ? Whb : Whf;
  const float* bhh = d ? bhhb : bhhf;
  bool useLds = ((size_t)3 * nu * kH2 * 4 <= 48 * 1024);
  const float *wr, *wz, *wn;
  if (useLds) {
    int q4 = kH2 / 4;
    int tot4 = 3 * nu * q4;
    for (int i4 = threadIdx.x; i4 < tot4; i4 += 256) {
      int r = i4 / q4;
      int k4 = i4 - r * q4;
      int g = r / nu, qq = r - g * nu;
      *(float4*)(wlds + (size_t)r * kH2 + k4 * 4) =
          *(const float4*)(Whh + (size_t)(g * kH2 + blk * nu + qq) * kH2 + k4 * 4);
    }
    __syncthreads();
    wr = wlds + (size_t)(0 * nu + q) * kH2;
    wz = wlds + (size_t)(1 * nu + q) * kH2;
    wn = wlds + (size_t)(2 * nu + q) * kH2;
  } else {
    wr = Whh + (size_t)(0 * kH2 + u) * kH2;
    wz = Whh + (size_t)(1 * kH2 + u) * kH2;
    wn = Whh + (size_t)(2 * kH2 + u) * kH2;
  }
  float br = bhh[u], bz = bhh[kH2 + u], bn = bhh[2 * kH2 + u];
  const int* myTok = tokens + (size_t)(b0 + b) * kLIN;
  for (int t = 0; t < kLIN; ++t) {
    int pp = t & 1;
    const float* hin = henc + (size_t)(pp * 2 + d) * kH2 * BC;
    float* hout = henc + (size_t)((1 - pp) * 2 + d) * kH2 * BC;
    float ar = br, az = bz, an = bn;
    for (int k = 0; k < kH2; k += 4) {
      float4 fr = *(const float4*)(wr + k);
      float4 fz = *(const float4*)(wz + k);
      float4 fn = *(const float4*)(wn + k);
      float h0v = hin[(k + 0) * BC + b], h1v = hin[(k + 1) * BC + b];
      float h2v = hin[(k + 2) * BC + b], h3v = hin[(k + 3) * BC + b];
      ar += h0v * fr.x + h1v * fr.y + h2v * fr.z + h3v * fr.w;
      az += h0v * fz.x + h1v * fz.y + h2v * fz.z + h3v * fz.w;
      an += h0v * fn.x + h1v * fn.y + h2v * fn.z + h3v * fn.w;
    }
    int v = myTok[t];
    const float* git = gi + (size_t)(v * 2 + d) * 768;
    float r = 1.f / (1.f + expf(-(git[u] + ar)));
    float z = 1.f / (1.f + expf(-(git[kH2 + u] + az)));
    float n = tanhf(git[2 * kH2 + u] + r * an);
    float hprev = hin[(size_t)u * BC + b];
    float hnew = (1.f - z) * n + z * hprev;
    hout[(size_t)u * BC + b] = hnew;
    enc[((size_t)b * kLIN + t) * kH + d * kH2 + u] = hnew;
    grid.sync();
  }
}

// Decoder: small grid (<=128 blocks: grid.sync is cheap there), block-stride
// over phase work items, 5 grid.syncs per timestep.
__global__ __launch_bounds__(256, 2)
void k_dec_persist(const float* encAll, const float* cW, const float* Ctab,
                   const float* dWi, const float* dWh, const float* dbi, const float* dbh,
                   const float* oW, const float* ob, const float* aW, const float* Atab,
                   const int* targets, const float* mask,
                   float* key, float* sc, float* pm, float* pd, float* pctx,
                   float* gt, float* ht, float* hr, float* lg,
                   int* tok, float* loss, float* out0, float* out1,
                   int BC, int lbc, int b0) {
  cg::grid_group grid = cg::this_grid();
  int tid = threadIdx.x;
  int G = gridDim.x;
  for (int t = 0; t < kT; ++t) {
    int pp = t & 1, np = 1 - pp;
    for (int wk = blockIdx.x; wk < BC * 8; wk += G)
      phaseA(wk >> 3, wk & 7, tid, encAll, key, sc, pm, pd, pctx);
    grid.sync();
    for (int wk = blockIdx.x; wk < BC; wk += G)
      phaseB(wk, tid, cW, Ctab, sc, pm, pd, pctx, tok, out1, gt, BC, b0, t);
    grid.sync();
    for (int wk = blockIdx.x; wk < 2 * BC; wk += G)
      phaseC(wk, tid, dWi, dWh, dbi, dbh, gt, ht, hr, BC, lbc, pp);
    grid.sync();
    for (int wk = blockIdx.x; wk < BC * 8; wk += G)
      phaseD(wk >> 3, wk & 7, tid, oW, ob, hr, lg, BC, np);
    grid.sync();
    for (int wk = blockIdx.x; wk < BC; wk += G)
      phaseE(wk, tid, aW, targets, mask, Atab, hr, lg, key, tok, loss,
             out0, BC, b0, t, np);
    grid.sync();
  }
}

// ======================= fallback per-step kernels =========================

__global__ __launch_bounds__(256)
void k_enc_step(const int* tokens, const float* Whf, const float* Whb,
                const float* bhhf, const float* bhhb, const float* gi,
                float* henc, float* enc, int t, int pp, int BC, int lbc, int b0) {
  int d = blockIdx.x >> lbc;
  int blk = blockIdx.x & (BC - 1);
  int b = threadIdx.x & (BC - 1), q = threadIdx.x >> lbc;
  int u = blk * (256 >> lbc) + q;
  const float* Whh = d ? Whb : Whf;
  const float* bhh = d ? bhhb : bhhf;
  const float* hin = henc + (size_t)(pp * 2 + d) * kH2 * BC;
  float* hout = henc + (size_t)((1 - pp) * 2 + d) * kH2 * BC;
  const float* wr = Whh + (size_t)(0 * kH2 + u) * kH2;
  const float* wz = Whh + (size_t)(1 * kH2 + u) * kH2;
  const float* wn = Whh + (size_t)(2 * kH2 + u) * kH2;
  float ar = bhh[u], az = bhh[kH2 + u], an = bhh[2 * kH2 + u];
  for (int k = 0; k < kH2; k += 4) {
    float4 fr = *(const float4*)(wr + k);
    float4 fz = *(const float4*)(wz + k);
    float4 fn = *(const float4*)(wn + k);
    float h0v = hin[(k + 0) * BC + b], h1v = hin[(k + 1) * BC + b];
    float h2v = hin[(k + 2) * BC + b], h3v = hin[(k + 3) * BC + b];
    ar += h0v * fr.x + h1v * fr.y + h2v * fr.z + h3v * fr.w;
    az += h0v * fz.x + h1v * fz.y + h2v * fz.z + h3v * fz.w;
    an += h0v * fn.x + h1v * fn.y + h2v * fn.z + h3v * fn.w;
  }
  int v = tokens[(size_t)(b0 + b) * kLIN + t];
  const float* git = gi + (size_t)(v * 2 + d) * 768;
  float r = 1.f / (1.f + expf(-(git[u] + ar)));
  float z = 1.f / (1.f + expf(-(git[kH2 + u] + az)));
  float n = tanhf(git[2 * kH2 + u] + r * an);
  float hprev = hin[(size_t)u * BC + b];
  float hnew = (1.f - z) * n + z * hprev;
  hout[(size_t)u * BC + b] = hnew;
  enc[((size_t)b * kLIN + t) * kH + d * kH2 + u] = hnew;
}

__global__ __launch_bounds__(256)
void k_scores(const float* encAll, const float* keyAll, float* sc,
              float* pm, float* pd, float* pctx) {
  phaseA(blockIdx.x >> 3, blockIdx.x & 7, threadIdx.x, encAll, keyAll, sc, pm, pd, pctx);
}

__global__ __launch_bounds__(256)
void k_ctx_g(const float* cW, const float* Ctab, const float* sc,
             const float* pm, const float* pd, const float* pctx,
             const int* tok, float* out1, float* gt, int BC, int b0, int t) {
  phaseB(blockIdx.x, threadIdx.x, cW, Ctab, sc, pm, pd, pctx, tok, out1, gt, BC, b0, t);
}

__global__ __launch_bounds__(256)
void k_gru(const float* Wih, const float* Whh, const float* bih, const float* bhh,
           const float* gt, float* ht, float* hr, int BC, int lbc, int pp) {
  phaseC(blockIdx.x, threadIdx.x, Wih, Whh, bih, bhh, gt, ht, hr, BC, lbc, pp);
}

__global__ __launch_bounds__(256)
void k_logits(const float* oW, const float* ob, const float* hr, float* lg,
              int BC, int np) {
  phaseD(blockIdx.x >> 3, blockIdx.x & 7, threadIdx.x, oW, ob, hr, lg, BC, np);
}

__global__ __launch_bounds__(256)
void k_finish(const float* aW, const int* targets, const float* mask,
              const float* Atab, const float* hr, const float* lg,
              float* key, int* tok, float* loss, float* out0,
              int BC, int b0, int t, int np) {
  phaseE(blockIdx.x, threadIdx.x, aW, targets, mask, Atab, hr, lg, key, tok,
         loss, out0, BC, b0, t, np);
}

// ----------------------------------------------------- decoder prologue
__global__ __launch_bounds__(256)
void k_prologue(const float* enc, const float* Atab, const float* aW,
                float* hr, float* ht, float* key, int* tok, int BC) {
  int b = blockIdx.x, tid = threadIdx.x;
  __shared__ float h[kH];
  const float* h0 = enc + ((size_t)b * kLIN + (kLIN - 1)) * kH;
  for (int k = tid; k < kH; k += 256) {
    float v = h0[k];
    h[k] = v;
    hr[(size_t)b * kH + k] = v;
    ht[(size_t)k * BC + b] = v;
  }
  if (tid == 0) tok[b] = kSTART;
  __syncthreads();
  const float* A = Atab + (size_t)kSTART * kH;
  for (int j = tid; j < kH; j += 256) {
    const float* row = aW + (size_t)j * 1024 + 512;
    float acc = A[j];
    for (int k = 0; k < kH; k += 4) {
      float4 f = *(const float4*)(row + k);
      acc += h[k] * f.x + h[k + 1] * f.y + h[k + 2] * f.z + h[k + 3] * f.w;
    }
    key[(size_t)b * kH + j] = acc;
  }
}

__global__ void k_loss_out(float* dst, const float* loss) {
  if (threadIdx.x == 0 && blockIdx.x == 0) *dst = *loss;
}

// ---------------------------------------------------------------------------
static int g_coop = -1;      // -1 unknown, 1 works, 0 rejected -> fallback

extern "C" void kernel_launch(void* const* d_in, const int* in_sizes, int n_in,
                              void* d_out, int out_size, void* d_ws, size_t ws_size,
                              hipStream_t stream) {
  (void)in_sizes; (void)n_in;
  const int*   tok_in = (const int*)d_in[0];
  const int*   tgt    = (const int*)d_in[1];
  const float* mask   = (const float*)d_in[2];
  const float* emb_j  = (const float*)d_in[3];
  const float* emb_c  = (const float*)d_in[4];
  const float* eWif   = (const float*)d_in[5];
  const float* eWhf   = (const float*)d_in[6];
  const float* ebif   = (const float*)d_in[7];
  const float* ebhf   = (const float*)d_in[8];
  const float* eWib   = (const float*)d_in[9];
  const float* eWhb   = (const float*)d_in[10];
  const float* ebib   = (const float*)d_in[11];
  const float* ebhb   = (const float*)d_in[12];
  const float* dWi    = (const float*)d_in[13];
  const float* dWh    = (const float*)d_in[14];
  const float* dbi    = (const float*)d_in[15];
  const float* dbh    = (const float*)d_in[16];
  const float* aW     = (const float*)d_in[17];
  const float* ab     = (const float*)d_in[18];
  const float* cW     = (const float*)d_in[19];
  const float* cb     = (const float*)d_in[20];
  const float* oW     = (const float*)d_in[21];
  const float* ob     = (const float*)d_in[22];
  float* ws   = (float*)d_ws;
  float* out0 = (float*)d_out;
  float* out1 = out0 + (size_t)kB * kT * kVC;

  // ---- workspace layout (floats); small state sized for BC=64 capacity
  const size_t GI = 0;
  const size_t A  = GI + 107520;            // 70*2*768
  const size_t C  = A + 1024000;            // 2000*512
  const size_t SMALL = C + 1024000;
  size_t o = SMALL;
  const size_t HENC = o; o += 4 * 256 * 64; // [2pp][2dir][256][BC]
  const size_t KEY  = o; o += 64 * 512;
  const size_t SC   = o; o += 64 * 1024;
  const size_t PM   = o; o += 512;
  const size_t PD   = o; o += 512;
  const size_t PCT  = o; o += 64 * 8 * 512;
  const size_t GT   = o; o += 512 * 64;
  const size_t HR   = o; o += 2 * 64 * 512;
  const size_t HT   = o; o += 2 * 512 * 64;
  const size_t LG   = o; o += 64 * 2000;
  const size_t TOKo = o; o += 64;
  const size_t LOSS = o; o += 1;
  const size_t ENC  = o;                    // + BC*1024*512
  const int small_n = (int)(ENC - SMALL);

  int BC = 64;
  while (BC > 8 && (ENC + (size_t)BC * kLIN * kH) * sizeof(float) > ws_size) BC >>= 1;
  int lbc = (BC == 64) ? 6 : (BC == 32) ? 5 : (BC == 16) ? 4 : 3;
  int NC = kB / BC;
  int nu = 256 >> lbc;
  size_t wbytes = (size_t)3 * nu * kH2 * 4;
  unsigned enc_smem = (wbytes <= 48 * 1024) ? (unsigned)wbytes : 0u;

  float* gi_p   = ws + GI;
  float* A_p    = ws + A;
  float* C_p    = ws + C;
  float* henc_p = ws + HENC;
  float* key_p  = ws + KEY;
  float* sc_p   = ws + SC;
  float* pm_p   = ws + PM;
  float* pd_p   = ws + PD;
  float* pct_p  = ws + PCT;
  float* gt_p   = ws + GT;
  float* hr_p   = ws + HR;
  float* ht_p   = ws + HT;
  float* lg_p   = ws + LG;
  float* loss_p = ws + LOSS;
  float* enc_p  = ws + ENC;
  int* tokp = (int*)(ws + TOKo);

  // grid.sync cost explodes with block count (measured ~6us @128 blocks,
  // ~95us @512): cap decoder coop grid at 128 blocks.
  int decGrid = 2 * BC;
  if (decGrid > 128) decGrid = 128;

  k_zero<<<(small_n + 255) / 256, 256, 0, stream>>>(ws + SMALL, small_n);
  k_gi_table<<<140, 256, 0, stream>>>(emb_j, eWif, eWib, ebif, ebib, gi_p);
  k_ac_emb<<<2000, 256, 0, stream>>>(emb_c, aW, ab, cW, cb, A_p, C_p);

  for (int c = 0; c < NC; c++) {
    int b0 = c * BC;
    k_zero<<<(4 * 256 * BC + 255) / 256, 256, 0, stream>>>(henc_p, 4 * 256 * BC);

    // ---------------- encoder: cooperative, else per-step fallback
    bool enc_done = false;
    if (g_coop != 0) {
      void* eargs[] = {(void*)&tok_in, (void*)&eWhf, (void*)&eWhb, (void*)&ebhf,
                       (void*)&ebhb, (void*)&gi_p, (void*)&henc_p, (void*)&enc_p,
                       (void*)&BC, (void*)&lbc, (void*)&b0};
      hipError_t e = hipLaunchCooperativeKernel(
          reinterpret_cast<void*>(k_enc_persist), dim3(2 * BC), dim3(256),
          eargs, enc_smem, stream);
      if (e == hipSuccess) { enc_done = true; if (g_coop < 0) g_coop = 1; }
      else { g_coop = 0; (void)hipGetLastError(); }
    }
    if (!enc_done) {
      for (int t = 0; t < kLIN; t++)
        k_enc_step<<<2 * BC, 256, 0, stream>>>(tok_in, eWhf, eWhb, ebhf, ebhb,
                                               gi_p, henc_p, enc_p,
                                               t, t & 1, BC, lbc, b0);
    }

    k_prologue<<<BC, 256, 0, stream>>>(enc_p, A_p, aW, hr_p, ht_p, key_p, tokp, BC);

    // ---------------- decoder: cooperative, else per-step fallback
    bool dec_done = false;
    if (g_coop != 0) {
      void* dargs[] = {(void*)&enc_p, (void*)&cW, (void*)&C_p, (void*)&dWi,
                       (void*)&dWh, (void*)&dbi, (void*)&dbh, (void*)&oW,
                       (void*)&ob, (void*)&aW, (void*)&A_p, (void*)&tgt,
                       (void*)&mask, (void*)&key_p, (void*)&sc_p, (void*)&pm_p,
                       (void*)&pd_p, (void*)&pct_p, (void*)&gt_p, (void*)&ht_p,
                       (void*)&hr_p, (void*)&lg_p, (void*)&tokp, (void*)&loss_p,
                       (void*)&out0, (void*)&out1, (void*)&BC, (void*)&lbc,
                       (void*)&b0};
      hipError_t e = hipLaunchCooperativeKernel(
          reinterpret_cast<void*>(k_dec_persist), dim3(decGrid), dim3(256),
          dargs, 0, stream);
      if (e == hipSuccess) { dec_done = true; if (g_coop < 0) g_coop = 1; }
      else { g_coop = 0; (void)hipGetLastError(); }
    }
    if (!dec_done) {
      for (int t = 0; t < kT; t++) {
        int pp = t & 1, np = 1 - pp;
        k_scores<<<BC * 8, 256, 0, stream>>>(enc_p, key_p, sc_p, pm_p, pd_p, pct_p);
        k_ctx_g<<<BC, 256, 0, stream>>>(cW, C_p, sc_p, pm_p, pd_p, pct_p,
                                        tokp, out1, gt_p, BC, b0, t);
        k_gru<<<2 * BC, 256, 0, stream>>>(dWi, dWh, dbi, dbh, gt_p,
                                          ht_p, hr_p, BC, lbc, pp);
        k_logits<<<BC * 8, 256, 0, stream>>>(oW, ob, hr_p, lg_p, BC, np);
        k_finish<<<BC, 256, 0, stream>>>(aW, tgt, mask, A_p, hr_p, lg_p,
                                         key_p, tokp, loss_p, out0,
                                         BC, b0, t, np);
      }
    }
  }
  k_loss_out<<<1, 64, 0, stream>>>(out0 + (size_t)out_size - 1, loss_p);
}